// Round 3
// baseline (304.569 us; speedup 1.0000x reference)
//
#include <hip/hip_runtime.h>
#include <cstdint>
#include <cstddef>

#define NN 8192
#define FI 128
#define FO 128
#define NCH 4
#define BK 1024           // K-tile staged in LDS (4 KB per row per tile)
#define NT (NN / BK)      // 8 K-tiles
#define SUBS (BK / 32)    // 32 MFMA k-steps per tile

typedef __attribute__((ext_vector_type(8))) __bf16 bf16x8;
typedef __attribute__((ext_vector_type(8))) short short8;
typedef __attribute__((ext_vector_type(4))) float f32x4;

static __device__ __forceinline__ f32x4 mfma16(bf16x8 a, bf16x8 b, f32x4 c) {
  return __builtin_amdgcn_mfma_f32_16x16x32_bf16(a, b, c, 0, 0, 0);
}

static __device__ __forceinline__ unsigned short f2bfu(float f) {
  union { __bf16 h; unsigned short u; } cv;
  cv.h = (__bf16)f;
  return cv.u;
}

static __device__ __forceinline__ bf16x8 cvt8v(f32x4 a, f32x4 b) {
  bf16x8 v;
  v[0] = (__bf16)a[0]; v[1] = (__bf16)a[1]; v[2] = (__bf16)a[2]; v[3] = (__bf16)a[3];
  v[4] = (__bf16)b[0]; v[5] = (__bf16)b[1]; v[6] = (__bf16)b[2]; v[7] = (__bf16)b[3];
  return v;
}

// ---------------------------------------------------------------------------
// Pack X (fp32 [8192][128]) into bf16 MFMA-B-fragment order:
// frag g = nt*256 + kk ; lane l holds X[kk*32 + (l>>4)*8 + j][nt*16 + (l&15)]
// ---------------------------------------------------------------------------
__global__ void gcs_pack_x(const float* __restrict__ X, unsigned short* __restrict__ PX) {
  int gid = blockIdx.x * 256 + threadIdx.x;   // 131072 threads
  int l   = gid & 63;
  int g   = gid >> 6;                          // 0..2047
  int kk  = g & 255;
  int nt  = g >> 8;
  int col = nt * 16 + (l & 15);
  int k0  = kk * 32 + (l >> 4) * 8;
  unsigned int w[4];
#pragma unroll
  for (int p = 0; p < 4; ++p) {
    unsigned short lo = f2bfu(X[(size_t)(k0 + 2 * p) * FI + col]);
    unsigned short hi = f2bfu(X[(size_t)(k0 + 2 * p + 1) * FI + col]);
    w[p] = (unsigned int)lo | ((unsigned int)hi << 16);
  }
  uint4 v = make_uint4(w[0], w[1], w[2], w[3]);
  ((uint4*)PX)[g * 64 + l] = v;
}

// ---------------------------------------------------------------------------
// Pack adj_W (fp32 [4][128][128]) into bf16 B-fragment order:
// frag g = c*32 + ot*4 + ks ; lane l holds adj_W[c][ks*32+(l>>4)*8+j][ot*16+(l&15)]
// ---------------------------------------------------------------------------
__global__ void gcs_pack_w(const float* __restrict__ AW, unsigned short* __restrict__ PW) {
  int gid = blockIdx.x * 256 + threadIdx.x;   // 8192 threads
  int l   = gid & 63;
  int g   = gid >> 6;                          // 0..127
  int ks  = g & 3;
  int ot  = (g >> 2) & 7;
  int c   = g >> 5;
  const float* base = AW + (size_t)c * FI * FO;
  int col = ot * 16 + (l & 15);
  int k0  = ks * 32 + (l >> 4) * 8;
  unsigned int w[4];
#pragma unroll
  for (int p = 0; p < 4; ++p) {
    unsigned short lo = f2bfu(base[(k0 + 2 * p) * FO + col]);
    unsigned short hi = f2bfu(base[(k0 + 2 * p + 1) * FO + col]);
    w[p] = (unsigned int)lo | ((unsigned int)hi << 16);
  }
  uint4 v = make_uint4(w[0], w[1], w[2], w[3]);
  ((uint4*)PW)[g * 64 + l] = v;
}

// ---------------------------------------------------------------------------
// acc[n][o] = b[o] + sum_f X[n][f] * W[f][o]   (fp32, exact path)
// ---------------------------------------------------------------------------
__global__ void gcs_xpart(const float* __restrict__ X, const float* __restrict__ W,
                          const float* __restrict__ b, float* __restrict__ acc) {
  int gid = blockIdx.x * 256 + threadIdx.x;   // 8192*128 threads
  int n = gid >> 7;
  int o = gid & 127;
  const float4* Xr = (const float4*)(X + (size_t)n * FI);
  float s = b[o];
#pragma unroll 4
  for (int f4 = 0; f4 < FI / 4; ++f4) {
    float4 xv = Xr[f4];
    s += xv.x * W[(f4 * 4 + 0) * FO + o];
    s += xv.y * W[(f4 * 4 + 1) * FO + o];
    s += xv.z * W[(f4 * 4 + 2) * FO + o];
    s += xv.w * W[(f4 * 4 + 3) * FO + o];
  }
  acc[gid] = s;
}

// ---------------------------------------------------------------------------
// Main: per (32-row tile, channel). BK=1024: per K-tile each wave prefetches
// its 8 rows x 4 KB contiguous into registers (nontemporal, 32 x float4),
// MFMAs consume the PREVIOUS tile from swizzled LDS meanwhile; cvt+ds_write
// after the barrier. LDS = 64 KB Abuf + 8 KB AXs -> 2 blocks/CU; ILP replaces
// TLP for latency hiding.
// ---------------------------------------------------------------------------
__global__ void __launch_bounds__(256, 2)
gcs_main(const float* __restrict__ adjs, const unsigned short* __restrict__ PX,
         const unsigned short* __restrict__ PW, float* __restrict__ acc) {
  const int rt  = blockIdx.x;      // 0..255 row tile
  const int c   = blockIdx.y;      // 0..3 channel
  const int tid = threadIdx.x;
  const int w   = tid >> 6;        // wave 0..3
  const int l   = tid & 63;
  const int lr  = l & 15;
  const int lk  = l >> 4;

  // A tile, bf16, row-major [32][1024]; byte = row*2048 + k*2, ^((row&7)<<4)
  __shared__ unsigned short Abuf[32 * BK];
  // AX tile, bf16, [32][128]; byte = row*256 + col*2, ^((row&7)<<4)
  __shared__ unsigned short AXs[32 * 128];

  const float* Ab = adjs + (size_t)c * NN * NN + (size_t)(rt * 32) * NN;

  const char* pX0 = (const char*)PX + (size_t)((w * 2 + 0) * 256) * 1024 + l * 16;
  const char* pX1 = (const char*)PX + (size_t)((w * 2 + 1) * 256) * 1024 + l * 16;

  f32x4 acc00 = {}, acc01 = {}, acc10 = {}, acc11 = {};

  // prefetch window: 8 rows x 2 halves x 2 float4 (statically indexed)
  f32x4 pf[8][4];

  // ---- prologue: prefetch tile 0 ----
#pragma unroll
  for (int r = 0; r < 8; ++r) {
    const float* p = Ab + (size_t)(w * 8 + r) * NN + (size_t)l * 8;
#pragma unroll
    for (int h = 0; h < 2; ++h) {
      pf[r][h * 2 + 0] = __builtin_nontemporal_load((const f32x4*)(p + h * 512));
      pf[r][h * 2 + 1] = __builtin_nontemporal_load((const f32x4*)(p + h * 512 + 4));
    }
  }

  for (int t = 0; t < NT; ++t) {
    // ---- cvt + store prefetched tile t to LDS (waits inserted here) ----
#pragma unroll
    for (int r = 0; r < 8; ++r) {
      int row = w * 8 + r;
#pragma unroll
      for (int h = 0; h < 2; ++h) {
        bf16x8 bv = cvt8v(pf[r][h * 2 + 0], pf[r][h * 2 + 1]);
        int byte = (row * (BK * 2) + h * 1024 + l * 16) ^ ((row & 7) << 4);
        *(short8*)((char*)Abuf + byte) = __builtin_bit_cast(short8, bv);
      }
    }
    __syncthreads();

    // ---- issue prefetch for tile t+1 (overlaps compute below) ----
    if (t + 1 < NT) {
#pragma unroll
      for (int r = 0; r < 8; ++r) {
        const float* p = Ab + (size_t)(w * 8 + r) * NN + (size_t)(t + 1) * BK + (size_t)l * 8;
#pragma unroll
        for (int h = 0; h < 2; ++h) {
          pf[r][h * 2 + 0] = __builtin_nontemporal_load((const f32x4*)(p + h * 512));
          pf[r][h * 2 + 1] = __builtin_nontemporal_load((const f32x4*)(p + h * 512 + 4));
        }
      }
    }

    // ---- compute: 32 k-substeps from LDS tile t ----
#pragma unroll 4
    for (int s = 0; s < SUBS; ++s) {
      int kb = (s * 32 + lk * 8) * 2;           // byte offset along k
      int r0 = lr, r1 = 16 + lr;
      int b0 = (r0 * (BK * 2) + kb) ^ ((r0 & 7) << 4);
      int b1 = (r1 * (BK * 2) + kb) ^ ((r1 & 7) << 4);
      bf16x8 A0 = __builtin_bit_cast(bf16x8, *(const short8*)((const char*)Abuf + b0));
      bf16x8 A1 = __builtin_bit_cast(bf16x8, *(const short8*)((const char*)Abuf + b1));
      int kkG = t * SUBS + s;
      bf16x8 B0 = __builtin_bit_cast(bf16x8, *(const short8*)(pX0 + (size_t)kkG * 1024));
      bf16x8 B1 = __builtin_bit_cast(bf16x8, *(const short8*)(pX1 + (size_t)kkG * 1024));
      acc00 = mfma16(A0, B0, acc00);
      acc01 = mfma16(A0, B1, acc01);
      acc10 = mfma16(A1, B0, acc10);
      acc11 = mfma16(A1, B1, acc11);
    }
    __syncthreads();
  }

  // ---- AX -> swizzled LDS (bf16) ----
#pragma unroll
  for (int mt = 0; mt < 2; ++mt) {
#pragma unroll
    for (int ntl = 0; ntl < 2; ++ntl) {
      f32x4 v = (mt == 0) ? (ntl == 0 ? acc00 : acc01)
                          : (ntl == 0 ? acc10 : acc11);
      int col = (w * 2 + ntl) * 16 + lr;
#pragma unroll
      for (int r = 0; r < 4; ++r) {
        int row  = mt * 16 + lk * 4 + r;
        int byte = (row * 256 + col * 2) ^ ((row & 7) << 4);
        *(unsigned short*)((char*)AXs + byte) = f2bfu(v[r]);
      }
    }
  }
  __syncthreads();

  // ---- projection: relu( AX[32x128] @ adjW_c[128x128] ) ----
  f32x4 p00 = {}, p01 = {}, p10 = {}, p11 = {};
  const bf16x8* pWc = (const bf16x8*)PW + (size_t)(c * 32) * 64;
#pragma unroll
  for (int ks = 0; ks < 4; ++ks) {
    int fb = (ks * 32 + lk * 8) * 2;
    int row0 = lr, row1 = 16 + lr;
    int byte0 = (row0 * 256 + fb) ^ ((row0 & 7) << 4);
    int byte1 = (row1 * 256 + fb) ^ ((row1 & 7) << 4);
    bf16x8 a0 = __builtin_bit_cast(bf16x8, *(const short8*)((const char*)AXs + byte0));
    bf16x8 a1 = __builtin_bit_cast(bf16x8, *(const short8*)((const char*)AXs + byte1));
    bf16x8 b0 = pWc[(size_t)((w * 2 + 0) * 4 + ks) * 64 + l];
    bf16x8 b1 = pWc[(size_t)((w * 2 + 1) * 4 + ks) * 64 + l];
    p00 = mfma16(a0, b0, p00);
    p01 = mfma16(a0, b1, p01);
    p10 = mfma16(a1, b0, p10);
    p11 = mfma16(a1, b1, p11);
  }

  // ---- relu per channel, atomic accumulate ----
#pragma unroll
  for (int mt = 0; mt < 2; ++mt) {
#pragma unroll
    for (int otl = 0; otl < 2; ++otl) {
      f32x4 v = (mt == 0) ? (otl == 0 ? p00 : p01)
                          : (otl == 0 ? p10 : p11);
      int o = (w * 2 + otl) * 16 + lr;
#pragma unroll
      for (int r = 0; r < 4; ++r) {
        int row_g = rt * 32 + mt * 16 + lk * 4 + r;
        float x = fmaxf(v[r], 0.0f);
        atomicAdd(&acc[(size_t)row_g * FO + o], x);
      }
    }
  }
}

// ---------------------------------------------------------------------------
// out = relu(acc)
// ---------------------------------------------------------------------------
__global__ void gcs_final(const float* __restrict__ acc, float* __restrict__ out) {
  int i = blockIdx.x * 256 + threadIdx.x;    // over float4s
  float4 v = ((const float4*)acc)[i];
  v.x = fmaxf(v.x, 0.0f);
  v.y = fmaxf(v.y, 0.0f);
  v.z = fmaxf(v.z, 0.0f);
  v.w = fmaxf(v.w, 0.0f);
  ((float4*)out)[i] = v;
}

extern "C" void kernel_launch(void* const* d_in, const int* in_sizes, int n_in,
                              void* d_out, int out_size, void* d_ws, size_t ws_size,
                              hipStream_t stream) {
  const float* X    = (const float*)d_in[0];   // [8192][128]
  const float* adjs = (const float*)d_in[1];   // [4][8192][8192]
  const float* W    = (const float*)d_in[2];   // [128][128]
  const float* AW   = (const float*)d_in[3];   // [4][128][128]
  const float* b    = (const float*)d_in[4];   // [128]
  float* out = (float*)d_out;

  char* ws = (char*)d_ws;
  float*          accbuf = (float*)ws;                          // 4 MB
  unsigned short* PX     = (unsigned short*)(ws + (4u << 20));  // 2 MB
  unsigned short* PW     = (unsigned short*)(ws + (6u << 20));  // 128 KB

  hipLaunchKernelGGL(gcs_pack_x, dim3(512),     dim3(256), 0, stream, X, PX);
  hipLaunchKernelGGL(gcs_pack_w, dim3(32),      dim3(256), 0, stream, AW, PW);
  hipLaunchKernelGGL(gcs_xpart,  dim3(4096),    dim3(256), 0, stream, X, W, b, accbuf);
  hipLaunchKernelGGL(gcs_main,   dim3(256, 4),  dim3(256), 0, stream, adjs, PX, PW, accbuf);
  hipLaunchKernelGGL(gcs_final,  dim3(1024),    dim3(256), 0, stream, accbuf, out);
}

// Round 4
// 209.575 us; speedup vs baseline: 1.4533x; 1.4533x over previous
//
#include <hip/hip_runtime.h>
#include <cstdint>
#include <cstddef>

#define NN 8192
#define FI 128
#define FO 128
#define NCH 4
#define HK 256              // k-range per LDS half-buffer
#define NH (NN / HK)        // 32 halves

typedef __attribute__((ext_vector_type(8))) __bf16 bf16x8;
typedef __attribute__((ext_vector_type(8))) short short8;
typedef __attribute__((ext_vector_type(4))) float f32x4;

static __device__ __forceinline__ f32x4 mfma16(bf16x8 a, bf16x8 b, f32x4 c) {
  return __builtin_amdgcn_mfma_f32_16x16x32_bf16(a, b, c, 0, 0, 0);
}

static __device__ __forceinline__ unsigned short f2bfu(float f) {
  union { __bf16 h; unsigned short u; } cv;
  cv.h = (__bf16)f;
  return cv.u;
}

static __device__ __forceinline__ unsigned int pack2(float a, float b) {
  return (unsigned int)f2bfu(a) | ((unsigned int)f2bfu(b) << 16);
}

// ---------------------------------------------------------------------------
// Pack X (fp32 [8192][128]) into bf16 MFMA-B-fragment order:
// frag g = nt*256 + kk ; lane l holds X[kk*32 + (l>>4)*8 + j][nt*16 + (l&15)]
// ---------------------------------------------------------------------------
__global__ void gcs_pack_x(const float* __restrict__ X, unsigned short* __restrict__ PX) {
  int gid = blockIdx.x * 256 + threadIdx.x;   // 131072 threads
  int l   = gid & 63;
  int g   = gid >> 6;                          // 0..2047
  int kk  = g & 255;
  int nt  = g >> 8;
  int col = nt * 16 + (l & 15);
  int k0  = kk * 32 + (l >> 4) * 8;
  unsigned int w[4];
#pragma unroll
  for (int p = 0; p < 4; ++p)
    w[p] = pack2(X[(size_t)(k0 + 2 * p) * FI + col], X[(size_t)(k0 + 2 * p + 1) * FI + col]);
  ((uint4*)PX)[g * 64 + l] = make_uint4(w[0], w[1], w[2], w[3]);
}

// ---------------------------------------------------------------------------
// Pack adj_W (fp32 [4][128][128]) into bf16 B-fragment order:
// frag g = c*32 + ot*4 + ks ; lane l holds adj_W[c][ks*32+(l>>4)*8+j][ot*16+(l&15)]
// ---------------------------------------------------------------------------
__global__ void gcs_pack_w(const float* __restrict__ AW, unsigned short* __restrict__ PW) {
  int gid = blockIdx.x * 256 + threadIdx.x;   // 8192 threads
  int l   = gid & 63;
  int g   = gid >> 6;                          // 0..127
  int ks  = g & 3;
  int ot  = (g >> 2) & 7;
  int c   = g >> 5;
  const float* base = AW + (size_t)c * FI * FO;
  int col = ot * 16 + (l & 15);
  int k0  = ks * 32 + (l >> 4) * 8;
  unsigned int w[4];
#pragma unroll
  for (int p = 0; p < 4; ++p)
    w[p] = pack2(base[(k0 + 2 * p) * FO + col], base[(k0 + 2 * p + 1) * FO + col]);
  ((uint4*)PW)[g * 64 + l] = make_uint4(w[0], w[1], w[2], w[3]);
}

// ---------------------------------------------------------------------------
// xpart[n][o] = b[o] + sum_f X[n][f] * W[f][o]   (fp32, exact path)
// ---------------------------------------------------------------------------
__global__ void gcs_xpart(const float* __restrict__ X, const float* __restrict__ W,
                          const float* __restrict__ b, float* __restrict__ xp) {
  int gid = blockIdx.x * 256 + threadIdx.x;   // 8192*128 threads
  int n = gid >> 7;
  int o = gid & 127;
  const float4* Xr = (const float4*)(X + (size_t)n * FI);
  float s = b[o];
#pragma unroll 4
  for (int f4 = 0; f4 < FI / 4; ++f4) {
    float4 xv = Xr[f4];
    s += xv.x * W[(f4 * 4 + 0) * FO + o];
    s += xv.y * W[(f4 * 4 + 1) * FO + o];
    s += xv.z * W[(f4 * 4 + 2) * FO + o];
    s += xv.w * W[(f4 * 4 + 3) * FO + o];
  }
  xp[gid] = s;
}

// ---------------------------------------------------------------------------
// Main (channel-fused, persistent 1 block/CU): block = 32-row tile, 8 waves.
// All 4 channels processed together: B-fragments (PX) read once, used 4x.
// K pipelined in 32 halves of 256, double-buffered LDS (2 x 64 KB); loads for
// half h+1 issued into regs before compute(h) -> HBM never idles; ONE barrier
// per iteration. Epilogue: per-channel relu(AX_c @ W_c) summed in regs,
// + xpart, relu, direct store (no atomics).
// ---------------------------------------------------------------------------
__global__ void __launch_bounds__(512, 2)
gcs_main(const float* __restrict__ adjs, const unsigned short* __restrict__ PX,
         const unsigned short* __restrict__ PW, const float* __restrict__ xpart,
         float* __restrict__ out) {
  const int rt  = blockIdx.x;      // 0..255 row tile
  const int tid = threadIdx.x;
  const int w   = tid >> 6;        // wave 0..7 (owns col-tile w)
  const int l   = tid & 63;
  const int lr  = l & 15;
  const int lk  = l >> 4;

  // 2 half-buffers, each [4ch][32 rows][256 k] bf16 = 64 KB, XOR-swizzled per
  // channel: byte_in_ch = (r*512 + k*2) ^ ((r&7)<<4)
  __shared__ unsigned short buf[2][NCH * 32 * HK];   // 128 KB

  // accumulators: AX[c][m] for rows m*16+lk*4+{0..3}, col w*16+lr
  f32x4 acc[NCH][2] = {};
  // prefetch regs: 16 (c,r) rows x 16 B/lane (1 KB/row wave-wide)
  f32x4 pf[16];

  // ---- staging helpers (fully unrolled, static indices) ----
#define LOADH(h2)                                                              \
  _Pragma("unroll") for (int j = 0; j < 16; ++j) {                             \
    int p = w * 16 + j; int c = p >> 5; int r = p & 31;                        \
    const float* src = adjs + (size_t)c * NN * NN +                            \
                       (size_t)(rt * 32 + r) * NN + (size_t)(h2) * HK + l * 4; \
    pf[j] = __builtin_nontemporal_load((const f32x4*)src);                     \
  }

#define CVTSTORE(dst)                                                          \
  _Pragma("unroll") for (int j = 0; j < 16; ++j) {                             \
    int p = w * 16 + j; int c = p >> 5; int r = p & 31;                        \
    unsigned int w0 = pack2(pf[j][0], pf[j][1]);                               \
    unsigned int w1 = pack2(pf[j][2], pf[j][3]);                               \
    int byte = c * 16384 + ((r * 512 + l * 8) ^ ((r & 7) << 4));               \
    *(uint2*)((char*)(dst) + byte) = make_uint2(w0, w1);                       \
  }

  // ---- prologue ----
  LOADH(0);
  CVTSTORE(buf[0]);
  LOADH(1);
  __syncthreads();

  // ---- main pipeline over 32 halves ----
  for (int h = 0; h < NH; ++h) {
    const char* bufC = (const char*)buf[h & 1];
#pragma unroll
    for (int s = 0; s < 8; ++s) {
      int kkG = h * 8 + s;
      bf16x8 B = *(const bf16x8*)((const char*)PX + ((size_t)(w * 256 + kkG) * 64 + l) * 16);
#pragma unroll
      for (int c = 0; c < NCH; ++c) {
#pragma unroll
        for (int m = 0; m < 2; ++m) {
          int r = m * 16 + lr;
          int byte = c * 16384 + ((r * 512 + s * 64 + lk * 16) ^ ((r & 7) << 4));
          bf16x8 A = __builtin_bit_cast(bf16x8, *(const short8*)(bufC + byte));
          acc[c][m] = mfma16(A, B, acc[c][m]);
        }
      }
    }
    if (h + 1 < NH) {
      CVTSTORE(buf[(h + 1) & 1]);     // waits on loads of half h+1
      if (h + 2 < NH) { LOADH(h + 2); }
    }
    __syncthreads();
  }

  // ---- epilogue: per channel relu(AX_c @ adjW_c), sum in regs ----
  char* AXs = (char*)buf;             // 8 KB reshape buffer (aliases buf)
  f32x4 osum0 = {}, osum1 = {};
#pragma unroll
  for (int c = 0; c < NCH; ++c) {
    __syncthreads();                  // previous channel's readers done
#pragma unroll
    for (int m = 0; m < 2; ++m) {
#pragma unroll
      for (int rr = 0; rr < 4; ++rr) {
        int row = m * 16 + lk * 4 + rr;
        int col = w * 16 + lr;
        int byte = (row * 256 + col * 2) ^ ((row & 7) << 4);
        *(unsigned short*)(AXs + byte) = f2bfu(acc[c][m][rr]);
      }
    }
    __syncthreads();
    f32x4 p0 = {}, p1 = {};
#pragma unroll
    for (int ks = 0; ks < 4; ++ks) {
      int kb = ks * 64 + lk * 16;
      int r0 = lr, r1 = 16 + lr;
      int b0 = (r0 * 256 + kb) ^ ((r0 & 7) << 4);
      int b1 = (r1 * 256 + kb) ^ ((r1 & 7) << 4);
      bf16x8 a0 = __builtin_bit_cast(bf16x8, *(const short8*)(AXs + b0));
      bf16x8 a1 = __builtin_bit_cast(bf16x8, *(const short8*)(AXs + b1));
      bf16x8 bw = *(const bf16x8*)((const char*)PW + ((size_t)(c * 32 + w * 4 + ks) * 64 + l) * 16);
      p0 = mfma16(a0, bw, p0);
      p1 = mfma16(a1, bw, p1);
    }
#pragma unroll
    for (int rr = 0; rr < 4; ++rr) {
      osum0[rr] += fmaxf(p0[rr], 0.0f);
      osum1[rr] += fmaxf(p1[rr], 0.0f);
    }
  }

  // ---- add x_part, final relu, store ----
#pragma unroll
  for (int m = 0; m < 2; ++m) {
#pragma unroll
    for (int rr = 0; rr < 4; ++rr) {
      int row = rt * 32 + m * 16 + lk * 4 + rr;
      int col = w * 16 + lr;
      float s = (m == 0 ? osum0[rr] : osum1[rr]) + xpart[(size_t)row * FO + col];
      out[(size_t)row * FO + col] = fmaxf(s, 0.0f);
    }
  }
}

extern "C" void kernel_launch(void* const* d_in, const int* in_sizes, int n_in,
                              void* d_out, int out_size, void* d_ws, size_t ws_size,
                              hipStream_t stream) {
  const float* X    = (const float*)d_in[0];   // [8192][128]
  const float* adjs = (const float*)d_in[1];   // [4][8192][8192]
  const float* W    = (const float*)d_in[2];   // [128][128]
  const float* AW   = (const float*)d_in[3];   // [4][128][128]
  const float* b    = (const float*)d_in[4];   // [128]
  float* out = (float*)d_out;

  char* ws = (char*)d_ws;
  float*          xpart = (float*)ws;                          // 4 MB
  unsigned short* PX    = (unsigned short*)(ws + (4u << 20));  // 2 MB
  unsigned short* PW    = (unsigned short*)(ws + (6u << 20));  // 128 KB

  hipLaunchKernelGGL(gcs_pack_x, dim3(512),  dim3(256), 0, stream, X, PX);
  hipLaunchKernelGGL(gcs_pack_w, dim3(32),   dim3(256), 0, stream, AW, PW);
  hipLaunchKernelGGL(gcs_xpart,  dim3(4096), dim3(256), 0, stream, X, W, b, xpart);
  hipLaunchKernelGGL(gcs_main,   dim3(256),  dim3(512), 0, stream, adjs, PX, PW, xpart, out);
}